// Round 2
// 158.049 us; speedup vs baseline: 1.1567x; 1.1567x over previous
//
#include <hip/hip_runtime.h>
#include <hip/hip_bf16.h>
#include <hip/hip_fp16.h>
#include <stdint.h>
#include <math.h>

#define NNODES 100000
#define HID 128
#define NEDGES 1000000
#define NEBLOCKS 15625  // edge blocks: 15625 * 4 waves * 16 edges = 1,000,000

typedef __attribute__((ext_vector_type(4))) float floatx4;
typedef _Float16 f16x2 __attribute__((ext_vector_type(2)));
typedef _Float16 f16x4 __attribute__((ext_vector_type(4)));
typedef _Float16 f16x8 __attribute__((ext_vector_type(8)));

// ---------------- Kernel 0: pack B = [W1_top | W1_bot] into MFMA fragment
// order, f16. Fragment: B[k=(lane>>4)*8+j][n=lane&15],
// element base ((ct*4+ks)*64+lane)*8, ct=0..15 (16-col tiles), ks=0..3.
__global__ __launch_bounds__(256) void pack_b_kernel(
    const float* __restrict__ W1, _Float16* __restrict__ Bf) {
  const int t = blockIdx.x * 256 + threadIdx.x;  // 0..4095
  const int lane = t & 63;
  const int ks = (t >> 6) & 3;
  const int ct = t >> 8;
  const int n = ct * 16 + (lane & 15);
  const int kb = ks * 32 + ((lane >> 4) * 8);
  f16x8 h;
#pragma unroll
  for (int j = 0; j < 8; ++j) {
    const int k = kb + j;
    const float v = (n < HID) ? W1[(size_t)k * HID + n]
                              : W1[(size_t)(HID + k) * HID + (n - HID)];
    h[j] = (_Float16)v;
  }
  *(f16x8*)(Bf + (size_t)t * 8) = h;
}

// ---------------- Kernel 1: node projection via single-pass f16 MFMA -------
// Block: 64 rows x 256 cols. Staging: fully-coalesced flat copy, in-register
// fp32->f16, LDS As[row][k] stride 136 halfs. One barrier, K-loop: A via
// ds_read_b128, B frags from L2-hot packed global, 64 MFMA/wave. Co aliases
// As for the epilogue. Epilogue quantizes each 128-ch half-row to biased
// uint8 with a per-half linear scale (max|v|/127), storing P (1 B/ch) and
// scalesInv[node][half]. This halves P bytes AND the edge kernel's random
// gather bytes vs f16, with ~3x less quant error than fp8 e4m3.
__global__ __launch_bounds__(256) void project_kernel(
    const float* __restrict__ emb, const _Float16* __restrict__ Bf,
    uint8_t* __restrict__ P, float* __restrict__ scalesInv) {
  __shared__ __align__(16) char smem[64 * 264 * 2];  // 33792 B
  _Float16* As = (_Float16*)smem;  // [row][k], stride 136 halfs (17408 B used)
  __half* Co = (__half*)smem;      // alias after K-loop, 64 x 264

  const int t = threadIdx.x;
  const int lane = t & 63;
  const int w = t >> 6;
  const int l16 = lane & 15;
  const int q = lane >> 4;
  const int row0 = blockIdx.x * 64;

  // ---- staging: load i covers flat float idx t*4 + i*1024 (wave-contiguous)
  {
    const int r_base = t >> 5;       // 0..7
    const int col = (t & 31) * 4;    // 0..124
#pragma unroll
    for (int i = 0; i < 8; ++i) {
      int grow = row0 + r_base + i * 8;
      if (grow >= NNODES) grow = NNODES - 1;
      const floatx4 v = *(const floatx4*)(emb + (size_t)grow * HID + col);
      f16x4 h;
      h[0] = (_Float16)v.x; h[1] = (_Float16)v.y;
      h[2] = (_Float16)v.z; h[3] = (_Float16)v.w;
      *(f16x4*)&As[(r_base + i * 8) * 136 + col] = h;
    }
  }
  __syncthreads();

  floatx4 acc[4][4] = {};  // [rt][ct]
#pragma unroll
  for (int ks = 0; ks < 4; ++ks) {
    f16x8 bh[4];
#pragma unroll
    for (int ct = 0; ct < 4; ++ct) {
      const size_t idx = (size_t)(((w * 4 + ct) * 4 + ks) * 64 + lane) * 8;
      bh[ct] = *(const f16x8*)(Bf + idx);
    }
    f16x8 ah[4];
#pragma unroll
    for (int rt = 0; rt < 4; ++rt)
      ah[rt] = *(const f16x8*)&As[(rt * 16 + l16) * 136 + ks * 32 + q * 8];
#pragma unroll
    for (int rt = 0; rt < 4; ++rt)
#pragma unroll
      for (int ct = 0; ct < 4; ++ct)
        acc[rt][ct] = __builtin_amdgcn_mfma_f32_16x16x32_f16(ah[rt], bh[ct], acc[rt][ct], 0, 0, 0);
  }

  // epilogue: C/D layout col=lane&15, row=(lane>>4)*4+reg -> LDS (f16).
  __syncthreads();  // As reads done; safe to alias Co
#pragma unroll
  for (int rt = 0; rt < 4; ++rt)
#pragma unroll
    for (int ct = 0; ct < 4; ++ct)
#pragma unroll
      for (int r = 0; r < 4; ++r) {
        const int row = rt * 16 + q * 4 + r;
        const int col = w * 64 + ct * 16 + l16;
        Co[row * 264 + col] = __float2half(acc[rt][ct][r]);
      }
  __syncthreads();
  // quantize + store: 64 rows x 16 chunks of 16 channels. The 8 threads
  // covering one (row, half) are lanes [8a..8a+7] -> shfl_xor 1/2/4 max.
#pragma unroll
  for (int i = 0; i < 4; ++i) {
    const int chunk = t + i * 256;
    const int row = chunk >> 4;    // 0..63
    const int cx = chunk & 15;     // 0..15 (16B chunk within row)
    const int half = cx >> 3;      // 0 = src-proj cols, 1 = tgt-proj cols
    const f16x8 v0 = *(const f16x8*)&Co[row * 264 + cx * 16];
    const f16x8 v1 = *(const f16x8*)&Co[row * 264 + cx * 16 + 8];
    float f[16];
#pragma unroll
    for (int k = 0; k < 8; ++k) { f[k] = (float)v0[k]; f[8 + k] = (float)v1[k]; }
    float m = 0.f;
#pragma unroll
    for (int k = 0; k < 16; ++k) m = fmaxf(m, fabsf(f[k]));
    m = fmaxf(m, __shfl_xor(m, 1, 64));
    m = fmaxf(m, __shfl_xor(m, 2, 64));
    m = fmaxf(m, __shfl_xor(m, 4, 64));
    m = fmaxf(m, 1e-20f);
    const float qs = 127.0f / m;
    const int grow = row0 + row;
    if (grow < NNODES) {
      if ((cx & 7) == 0) scalesInv[2 * grow + half] = m * (1.0f / 127.0f);
      unsigned d[4];
#pragma unroll
      for (int dw = 0; dw < 4; ++dw) {
        unsigned acc_b = 0;
#pragma unroll
        for (int b = 0; b < 4; ++b) {
          int qv = (int)rintf(f[dw * 4 + b] * qs) + 128;
          qv = qv < 0 ? 0 : (qv > 255 ? 255 : qv);
          acc_b |= ((unsigned)qv) << (8 * b);
        }
        d[dw] = acc_b;
      }
      uint4 o; o.x = d[0]; o.y = d[1]; o.z = d[2]; o.w = d[3];
      *(uint4*)(P + (size_t)grow * 256 + cx * 16) = o;
    }
  }
}

// ---------------- Kernel 2: per-edge MLP + exp --------------------
// Exact-fit grid: 15625 blocks x 4 waves x 16 edges = 1,000,000.
// 16 lanes/edge, 8 channels/lane. P is biased uint8 with per-node-half
// scales: v = (u - 128) * inv. Gather = 8 B/lane (dwordx2) = one 128 B
// line per endpoint. Scales (800 KB) stay L2-resident; 16 lanes broadcast-
// load the same scale address. Math in f32 FMA:
//   pre = su*ssinv + tu*stinv + (b1[ch] - 128*(ssinv+stinv))
__global__ __launch_bounds__(256) void edge_kernel(
    const uint8_t* __restrict__ P, const float* __restrict__ scalesInv,
    const int* __restrict__ lm,
    const float* __restrict__ b1, const float* __restrict__ W2,
    const float* __restrict__ b2, float* __restrict__ explog,
    float* __restrict__ partials) {
  const int lane = threadIdx.x & 63;
  const int wid = threadIdx.x >> 6;
  const int g = lane >> 4;    // edge sub-group 0..3
  const int l16 = lane & 15;
  const int c = l16 * 8;      // 8 channels per lane (== byte offset into half)

  float b1f[8], w2f[8];
  {
    const floatx4 b1a = *(const floatx4*)(b1 + c);
    const floatx4 b1b = *(const floatx4*)(b1 + c + 4);
    const floatx4 w2a = *(const floatx4*)(W2 + c);
    const floatx4 w2b = *(const floatx4*)(W2 + c + 4);
    b1f[0] = b1a.x; b1f[1] = b1a.y; b1f[2] = b1a.z; b1f[3] = b1a.w;
    b1f[4] = b1b.x; b1f[5] = b1b.y; b1f[6] = b1b.z; b1f[7] = b1b.w;
    w2f[0] = w2a.x; w2f[1] = w2a.y; w2f[2] = w2a.z; w2f[3] = w2a.w;
    w2f[4] = w2b.x; w2f[5] = w2b.y; w2f[6] = w2b.z; w2f[7] = w2b.w;
  }
  const float b2v = b2[0];

  const int e0 = (blockIdx.x * 4 + wid) * 16;

  uint2 rs[4], rt_[4];
  float ssv[4], stv[4];
#pragma unroll
  for (int j = 0; j < 4; ++j) {
    const int ej = e0 + j * 4 + g;
    const int src = lm[ej];
    const int tgt = lm[NEDGES + ej];
    rs[j]  = *(const uint2*)(P + (size_t)src * 256 + c);
    rt_[j] = *(const uint2*)(P + (size_t)tgt * 256 + 128 + c);
    ssv[j] = scalesInv[2 * src];
    stv[j] = scalesInv[2 * tgt + 1];
  }
  float lsum = 0.f;
#pragma unroll
  for (int j = 0; j < 4; ++j) {
    const float si = ssv[j], ti = stv[j];
    const float cb = -128.0f * (si + ti);
    float p = 0.f;
    const unsigned su[2] = {rs[j].x, rs[j].y};
    const unsigned tu[2] = {rt_[j].x, rt_[j].y};
#pragma unroll
    for (int w = 0; w < 2; ++w) {
#pragma unroll
      for (int b = 0; b < 4; ++b) {
        const float sf = (float)((su[w] >> (8 * b)) & 0xffu);
        const float tf = (float)((tu[w] >> (8 * b)) & 0xffu);
        const int ch = w * 4 + b;
        const float pre = fmaf(sf, si, fmaf(tf, ti, b1f[ch] + cb));
        p = fmaf(fmaxf(pre, 0.f), w2f[ch], p);
      }
    }
    p += __shfl_xor(p, 8, 64);
    p += __shfl_xor(p, 4, 64);
    p += __shfl_xor(p, 2, 64);
    p += __shfl_xor(p, 1, 64);
    if (l16 == j) {
      const float ev = __expf(p + b2v);
      explog[e0 + j * 4 + g] = ev;
      lsum += ev;
    }
  }

#pragma unroll
  for (int off = 32; off >= 1; off >>= 1) lsum += __shfl_xor(lsum, off, 64);
  __shared__ float wsums[4];
  if (lane == 0) wsums[wid] = lsum;
  __syncthreads();
  if (threadIdx.x == 0)
    partials[blockIdx.x] = wsums[0] + wsums[1] + wsums[2] + wsums[3];
}

// ---------------- Kernel 2.5: reduce partials -> accum (single block) ------
__global__ __launch_bounds__(256) void reduce_kernel(
    const float* __restrict__ partials, float* __restrict__ accum) {
  float s = 0.f;
  for (int i = threadIdx.x; i < 3906; i += 256) {
    const floatx4 v = *(const floatx4*)(partials + i * 4);
    s += (v.x + v.y) + (v.z + v.w);
  }
  if (threadIdx.x == 0) s += partials[15624];
#pragma unroll
  for (int off = 32; off >= 1; off >>= 1) s += __shfl_xor(s, off, 64);
  __shared__ float ws_[4];
  if ((threadIdx.x & 63) == 0) ws_[threadIdx.x >> 6] = s;
  __syncthreads();
  if (threadIdx.x == 0) accum[0] = ws_[0] + ws_[1] + ws_[2] + ws_[3];
}

// ---------------- Kernel 3: normalize ----------------
__global__ __launch_bounds__(256) void norm_kernel(
    const float* __restrict__ explog, const float* __restrict__ sum_accum,
    float* __restrict__ out) {
  const float inv = 1.0f / *sum_accum;
  const int i = (blockIdx.x * 256 + threadIdx.x) * 4;
  if (i < NEDGES) {
    floatx4 v = *(const floatx4*)(explog + i);
    v.x *= inv; v.y *= inv; v.z *= inv; v.w *= inv;
    *(floatx4*)(out + i) = v;
  }
}

extern "C" void kernel_launch(void* const* d_in, const int* in_sizes, int n_in,
                              void* d_out, int out_size, void* d_ws, size_t ws_size,
                              hipStream_t stream) {
  const float* emb = (const float*)d_in[0];
  const int*   lm  = (const int*)d_in[1];   // [2, 1M]: sources then targets
  const float* W1  = (const float*)d_in[2];
  const float* b1  = (const float*)d_in[3];
  const float* W2  = (const float*)d_in[4];
  const float* b2  = (const float*)d_in[5];
  float* out = (float*)d_out;

  char* ws = (char*)d_ws;
  uint8_t* P      = (uint8_t*)ws;                  // 25,600,000 B (uint8 biased)
  float* accum    = (float*)(ws + 25600000);       // 256 B
  float* explog   = (float*)(ws + 25600256);       // 4,000,000 B
  _Float16* Bf    = (_Float16*)(ws + 29600256);    // 65,536 B
  float* partials = (float*)(ws + 29665792);       // 62,500 B (pad to 62,720)
  float* scalesInv = (float*)(ws + 29728512);      // 800,000 B

  pack_b_kernel<<<16, 256, 0, stream>>>(W1, Bf);
  project_kernel<<<1563, 256, 0, stream>>>(emb, Bf, P, scalesInv);
  edge_kernel<<<NEBLOCKS, 256, 0, stream>>>(P, scalesInv, lm, b1, W2, b2, explog, partials);
  reduce_kernel<<<1, 256, 0, stream>>>(partials, accum);
  norm_kernel<<<977, 256, 0, stream>>>(explog, accum, out);
}